// Round 2
// baseline (19.428 us; speedup 1.0000x reference)
//
#include <hip/hip_runtime.h>

constexpr int WIDTH       = 1000;
constexpr int N_PIXELS    = 1000 * 1000;
constexpr int PATCH_SIZE  = 5;
constexpr int PATCHES_X   = WIDTH / PATCH_SIZE;   // 200
constexpr int N_SEGMENTS  = N_PIXELS / PATCH_SIZE; // 200000 threads, 5 px each

// out[c, n] = sum_t sum_d coeff[patch(n), c, t, d] * pix[n, d]^t + bias[patch(n), c]
// Thread t handles pixels [5t, 5t+5) — one patch-row segment, single patch.
__global__ __launch_bounds__(256) void ts_approx_kernel(
    const float* __restrict__ pix,      // [N, 2]
    const float* __restrict__ coef,     // [NUM_PATCHES, 3, 10, 2] -> 60 floats / patch
    const float* __restrict__ bias,     // [NUM_PATCHES, 3]
    float* __restrict__ out)            // [3, N]
{
    int t = blockIdx.x * blockDim.x + threadIdx.x;
    if (t >= N_SEGMENTS) return;

    int n0   = t * PATCH_SIZE;          // first pixel of this segment
    int row  = t / PATCHES_X;           // = pixel row (since 200 segments/row)
    int col5 = t - row * PATCHES_X;     // patch column
    int patch = (row / PATCH_SIZE) * PATCHES_X + col5;

    // Coefficients for this patch: 3 channels x 5 float4 chunks (t pairs)
    const float4* c4 = reinterpret_cast<const float4*>(coef + (long)patch * 60);
    float4 cf[15];
    #pragma unroll
    for (int i = 0; i < 15; ++i) cf[i] = c4[i];

    const float* bg = bias + (long)patch * 3;
    float b0 = bg[0], b1 = bg[1], b2 = bg[2];

    // 5 pixel coordinate pairs
    const float2* p2 = reinterpret_cast<const float2*>(pix) + n0;
    float2 p[PATCH_SIZE];
    #pragma unroll
    for (int i = 0; i < PATCH_SIZE; ++i) p[i] = p2[i];

    #pragma unroll
    for (int px = 0; px < PATCH_SIZE; ++px) {
        float x = p[px].x, y = p[px].y;
        float a0 = b0, a1 = b1, a2 = b2;
        float xt = 1.0f, yt = 1.0f;     // x^(2i), y^(2i)
        #pragma unroll
        for (int i = 0; i < 5; ++i) {
            float xt1 = xt * x, yt1 = yt * y;   // x^(2i+1), y^(2i+1)
            float4 v0 = cf[i];                   // channel 0, t=2i / 2i+1
            a0 = fmaf(v0.x, xt,  a0); a0 = fmaf(v0.y, yt,  a0);
            a0 = fmaf(v0.z, xt1, a0); a0 = fmaf(v0.w, yt1, a0);
            float4 v1 = cf[5 + i];               // channel 1
            a1 = fmaf(v1.x, xt,  a1); a1 = fmaf(v1.y, yt,  a1);
            a1 = fmaf(v1.z, xt1, a1); a1 = fmaf(v1.w, yt1, a1);
            float4 v2 = cf[10 + i];              // channel 2
            a2 = fmaf(v2.x, xt,  a2); a2 = fmaf(v2.y, yt,  a2);
            a2 = fmaf(v2.z, xt1, a2); a2 = fmaf(v2.w, yt1, a2);
            xt = xt1 * x; yt = yt1 * y;          // advance to x^(2i+2)
        }
        int n = n0 + px;
        out[0 * N_PIXELS + n] = a0;
        out[1 * N_PIXELS + n] = a1;
        out[2 * N_PIXELS + n] = a2;
    }
}

extern "C" void kernel_launch(void* const* d_in, const int* in_sizes, int n_in,
                              void* d_out, int out_size, void* d_ws, size_t ws_size,
                              hipStream_t stream) {
    const float* pix  = (const float*)d_in[0];
    const float* coef = (const float*)d_in[1];
    const float* bias = (const float*)d_in[2];
    float* out = (float*)d_out;

    const int block = 256;
    const int grid = (N_SEGMENTS + block - 1) / block;
    ts_approx_kernel<<<grid, block, 0, stream>>>(pix, coef, bias, out);
}

// Round 3
// 13.118 us; speedup vs baseline: 1.4810x; 1.4810x over previous
//
#include <hip/hip_runtime.h>

constexpr int WIDTH     = 1000;
constexpr int HEIGHT    = 1000;
constexpr int N_PIXELS  = WIDTH * HEIGHT;
constexpr int PATCH     = 5;
constexpr int PATCHES_X = WIDTH / PATCH;      // 200
constexpr int BLOCK     = 256;
constexpr int MAXP      = BLOCK / PATCH + 2;  // 53 patches max per block

// out[c, n] = sum_t sum_d coeff[patch(n), c, t, d] * pix[n, d]^t + bias[patch(n), c]
// Block (bx, by): image row `by`, columns [bx*256, bx*256+255]. One patch-row
// per block -> contiguous patch range -> contiguous coalesced LDS stage.
__global__ __launch_bounds__(256) void ts_approx_kernel(
    const float* __restrict__ pix,      // [N, 2]
    const float* __restrict__ coef,     // [NUM_PATCHES, 3, 10, 2] = 60 floats/patch
    const float* __restrict__ bias,     // [NUM_PATCHES, 3]
    float* __restrict__ out)            // [3, N]
{
    __shared__ float scoef[MAXP * 60];
    __shared__ float sbias[MAXP * 3];

    const int tid  = threadIdx.x;
    const int row  = blockIdx.y;
    const int c0   = blockIdx.x * BLOCK;
    const int prow = row / PATCH;                              // uniform
    const int p0   = c0 / PATCH;                               // uniform
    const int pend = min(c0 + BLOCK - 1, WIDTH - 1) / PATCH;   // uniform
    const int np   = pend - p0 + 1;                            // <= 52

    // Stage coefficients: np*60 contiguous floats, coalesced float4 loads.
    const float4* g4 = reinterpret_cast<const float4*>(coef + (size_t)(prow * PATCHES_X + p0) * 60);
    float4* s4 = reinterpret_cast<float4*>(scoef);
    const int nf4 = np * 15;
    for (int j = tid; j < nf4; j += BLOCK) s4[j] = g4[j];

    // Stage bias: np*3 contiguous floats.
    const float* gb = bias + (size_t)(prow * PATCHES_X + p0) * 3;
    for (int j = tid; j < np * 3; j += BLOCK) sbias[j] = gb[j];

    __syncthreads();

    const int col = c0 + tid;
    if (col >= WIDTH) return;
    const int n = row * WIDTH + col;

    const float2 p = reinterpret_cast<const float2*>(pix)[n];
    const float x = p.x, y = p.y;

    const int pl = col / PATCH - p0;                 // local patch index
    const float4* c4 = reinterpret_cast<const float4*>(scoef + pl * 60);
    float a0 = sbias[pl * 3 + 0];
    float a1 = sbias[pl * 3 + 1];
    float a2 = sbias[pl * 3 + 2];

    float xt = 1.0f, yt = 1.0f;                      // x^(2i), y^(2i)
    #pragma unroll
    for (int i = 0; i < 5; ++i) {
        const float xt1 = xt * x, yt1 = yt * y;      // x^(2i+1), y^(2i+1)
        const float4 v0 = c4[i];                     // channel 0
        a0 = fmaf(v0.x, xt,  a0); a0 = fmaf(v0.y, yt,  a0);
        a0 = fmaf(v0.z, xt1, a0); a0 = fmaf(v0.w, yt1, a0);
        const float4 v1 = c4[5 + i];                 // channel 1
        a1 = fmaf(v1.x, xt,  a1); a1 = fmaf(v1.y, yt,  a1);
        a1 = fmaf(v1.z, xt1, a1); a1 = fmaf(v1.w, yt1, a1);
        const float4 v2 = c4[10 + i];                // channel 2
        a2 = fmaf(v2.x, xt,  a2); a2 = fmaf(v2.y, yt,  a2);
        a2 = fmaf(v2.z, xt1, a2); a2 = fmaf(v2.w, yt1, a2);
        xt = xt1 * x; yt = yt1 * y;
    }

    out[0 * N_PIXELS + n] = a0;
    out[1 * N_PIXELS + n] = a1;
    out[2 * N_PIXELS + n] = a2;
}

extern "C" void kernel_launch(void* const* d_in, const int* in_sizes, int n_in,
                              void* d_out, int out_size, void* d_ws, size_t ws_size,
                              hipStream_t stream) {
    const float* pix  = (const float*)d_in[0];
    const float* coef = (const float*)d_in[1];
    const float* bias = (const float*)d_in[2];
    float* out = (float*)d_out;

    dim3 grid((WIDTH + BLOCK - 1) / BLOCK, HEIGHT);   // (4, 1000)
    ts_approx_kernel<<<grid, BLOCK, 0, stream>>>(pix, coef, bias, out);
}

// Round 4
// 11.719 us; speedup vs baseline: 1.6578x; 1.1194x over previous
//
#include <hip/hip_runtime.h>

constexpr int WIDTH     = 1000;
constexpr int HEIGHT    = 1000;
constexpr int N_PIXELS  = WIDTH * HEIGHT;
constexpr int PATCH     = 5;
constexpr int PATCHES_X = WIDTH / PATCH;      // 200
constexpr int BLOCK     = 256;
constexpr int MAXP      = BLOCK / PATCH + 2;  // 53 patches max per block

// out[c, n] = sum_t sum_d coeff[patch(n), c, t, d] * pix[n, d]^t + bias[patch(n), c]
// Block (bx, py): 5-row band [5*py, 5*py+5) x cols [bx*256, ...). Thread = one
// column of the band: 5 vertical pixels, all in ONE patch -> coef loaded from
// LDS once per 5 pixels into VGPRs. All global accesses stay lane-coalesced.
__global__ __launch_bounds__(256) void ts_approx_kernel(
    const float* __restrict__ pix,      // [N, 2]
    const float* __restrict__ coef,     // [NUM_PATCHES, 3, 10, 2] = 60 floats/patch
    const float* __restrict__ bias,     // [NUM_PATCHES, 3]
    float* __restrict__ out)            // [3, N]
{
    __shared__ float scoef[MAXP * 60];
    __shared__ float sbias[MAXP * 3];

    const int tid  = threadIdx.x;
    const int prow = blockIdx.y;                               // patch row, 0..199
    const int c0   = blockIdx.x * BLOCK;
    const int p0   = c0 / PATCH;                               // uniform
    const int pend = min(c0 + BLOCK - 1, WIDTH - 1) / PATCH;   // uniform
    const int np   = pend - p0 + 1;                            // <= 52

    // Stage this patch-row slice: np*60 contiguous floats, coalesced float4.
    const float4* g4 = reinterpret_cast<const float4*>(coef + (size_t)(prow * PATCHES_X + p0) * 60);
    float4* s4 = reinterpret_cast<float4*>(scoef);
    const int nf4 = np * 15;
    for (int j = tid; j < nf4; j += BLOCK) s4[j] = g4[j];
    const float* gb = bias + (size_t)(prow * PATCHES_X + p0) * 3;
    for (int j = tid; j < np * 3; j += BLOCK) sbias[j] = gb[j];
    __syncthreads();

    const int col = c0 + tid;
    if (col >= WIDTH) return;

    const int row0 = prow * PATCH;
    const int pl   = col / PATCH - p0;             // local patch index

    // Coefficients for this thread's single patch -> 60 VGPRs, read once.
    float4 cf[15];
    const float4* c4 = reinterpret_cast<const float4*>(scoef + pl * 60);
    #pragma unroll
    for (int i = 0; i < 15; ++i) cf[i] = c4[i];
    const float b0 = sbias[pl * 3 + 0];
    const float b1 = sbias[pl * 3 + 1];
    const float b2 = sbias[pl * 3 + 2];

    const float2* p2 = reinterpret_cast<const float2*>(pix);

    #pragma unroll
    for (int r = 0; r < PATCH; ++r) {
        const int n = (row0 + r) * WIDTH + col;
        const float2 p = p2[n];
        const float x = p.x, y = p.y;

        float a0 = b0, a1 = b1, a2 = b2;
        float xt = 1.0f, yt = 1.0f;                // x^(2i), y^(2i)
        #pragma unroll
        for (int i = 0; i < 5; ++i) {
            const float xt1 = xt * x, yt1 = yt * y;
            float4 v = cf[i];                      // channel 0
            a0 = fmaf(v.x, xt,  a0); a0 = fmaf(v.y, yt,  a0);
            a0 = fmaf(v.z, xt1, a0); a0 = fmaf(v.w, yt1, a0);
            v = cf[5 + i];                         // channel 1
            a1 = fmaf(v.x, xt,  a1); a1 = fmaf(v.y, yt,  a1);
            a1 = fmaf(v.z, xt1, a1); a1 = fmaf(v.w, yt1, a1);
            v = cf[10 + i];                        // channel 2
            a2 = fmaf(v.x, xt,  a2); a2 = fmaf(v.y, yt,  a2);
            a2 = fmaf(v.z, xt1, a2); a2 = fmaf(v.w, yt1, a2);
            xt = xt1 * x; yt = yt1 * y;
        }

        out[0 * N_PIXELS + n] = a0;
        out[1 * N_PIXELS + n] = a1;
        out[2 * N_PIXELS + n] = a2;
    }
}

extern "C" void kernel_launch(void* const* d_in, const int* in_sizes, int n_in,
                              void* d_out, int out_size, void* d_ws, size_t ws_size,
                              hipStream_t stream) {
    const float* pix  = (const float*)d_in[0];
    const float* coef = (const float*)d_in[1];
    const float* bias = (const float*)d_in[2];
    float* out = (float*)d_out;

    dim3 grid((WIDTH + BLOCK - 1) / BLOCK, HEIGHT / PATCH);   // (4, 200)
    ts_approx_kernel<<<grid, BLOCK, 0, stream>>>(pix, coef, bias, out);
}